// Round 1
// baseline (292.888 us; speedup 1.0000x reference)
//
#include <hip/hip_runtime.h>

// Problem constants (fixed by setup_inputs)
constexpr int B = 4;
constexpr int C = 64;    // input channels
constexpr int O = 64;    // output channels (main conv)
constexpr int OOFF = 18; // offset channels = 2*3*3
constexpr int H = 192;
constexpr int W = 192;

typedef __attribute__((ext_vector_type(8))) short short8;   // 8 bf16 = 4 VGPR
typedef __attribute__((ext_vector_type(4))) float float4v;  // MFMA acc
typedef __attribute__((ext_vector_type(2))) float f32x2;    // v_pk_fma_f32 pair
typedef __attribute__((ext_vector_type(2))) uint u32x2;
typedef __attribute__((ext_vector_type(2))) __bf16 bf16x2;

__device__ inline ushort f2bf(float f) { // RNE via HW __bf16 convert
  return __builtin_bit_cast(ushort, (__bf16)f);
}
__device__ inline uint pk2bf(float lo, float hi) { // pack 2 bf16 (RNE)
  bf16x2 v;
  v.x = (__bf16)lo;
  v.y = (__bf16)hi;
  return __builtin_bit_cast(uint, v);
}
__device__ inline f32x2 upk(uint u) { // unpack 2 bf16 -> 2 f32
  u32x2 t;
  t.x = u << 16;
  t.y = u & 0xffff0000u;
  return __builtin_bit_cast(f32x2, t);
}

// -------------------------------------------------------------------------
// Kernel PRE (fused): blocks [0,9216): transpose x fp32 NCHW -> xtb bf16
// channels-last. [9216,9360): w_conv -> wBf (PERMUTED n-map oc = nt+4*col).
// [9360,9432): w_off -> wOf (plain n-map, N padded 18->32).
// -------------------------------------------------------------------------
__global__ __launch_bounds__(256) void k_pre(const float* __restrict__ x,
                                             ushort* __restrict__ xtb,
                                             const float* __restrict__ w_conv,
                                             ushort* __restrict__ wBf,
                                             const float* __restrict__ w_off,
                                             ushort* __restrict__ wOf) {
  __shared__ float tile[64][17];
  const int bid = blockIdx.x;
  const int tid = threadIdx.x;
  if (bid < 9216) { // transpose
    const int w0 = (bid % 12) * 16;
    const int h = (bid / 12) % 192;
    const int b = bid / 2304;
    const int wl = tid & 15;
    const int c0 = tid >> 4;
#pragma unroll
    for (int r = 0; r < 4; ++r) {
      const int c = c0 + r * 16;
      tile[c][wl] = x[(((size_t)b * C + c) * H + h) * W + w0 + wl];
    }
    __syncthreads();
    const int c = tid & 63;
    const int qq = tid >> 6;
#pragma unroll
    for (int r = 0; r < 4; ++r) {
      const int wq = qq + r * 4;
      xtb[(((size_t)b * H + h) * W + w0 + wq) * C + c] = f2bf(tile[c][wq]);
    }
  } else if (bid < 9360) { // wBf: 36864 entries
    const int i = (bid - 9216) * 256 + tid;
    const int j = i & 7;
    const int lane = (i >> 3) & 63;
    const int nt = (i >> 9) & 3;
    const int kstep = (i >> 11) & 1;
    const int kk = i >> 12;
    const int n = nt + 4 * (lane & 15); // permuted
    const int c = kstep * 32 + ((lane >> 4) & 3) * 8 + j;
    wBf[i] = f2bf(w_conv[((size_t)n * C + c) * 9 + kk]);
  } else { // wOf: 18432 entries
    const int i = (bid - 9360) * 256 + tid;
    const int j = i & 7;
    const int lane = (i >> 3) & 63;
    const int nt = (i >> 9) & 1;
    const int ks = (i >> 10) & 1;
    const int kk = i >> 11;
    const int n = nt * 16 + (lane & 15);
    const int c = ks * 32 + ((lane >> 4) & 3) * 8 + j;
    wOf[i] = (n < OOFF) ? f2bf(w_off[((size_t)n * C + c) * 9 + kk]) : (ushort)0;
  }
}

// -------------------------------------------------------------------------
// Kernel FUSED: offset-conv + deformable conv, BARRIER-FREE.
// 8x8 px tile, 256 threads = 4 waves. All LDS exchange is intra-wave
// (gather thread (p,qtr) and MFMA lane for pixel p&15 share a wave), so no
// __syncthreads anywhere — waves run fully decoupled pipelines.
// THIS REV: register diet to get under the 64-VGPR occupancy cliff
// (68 VGPR -> 4 waves/SIMD was the measured limiter: MfmaUtil 7%,
// VALUBusy 29%, HBM 4%, Occupancy 31% = pure latency-bound).
//  - gather split into two 8-channel chunks (32 data regs, not 64)
//  - phase-1 weight fragments loaded inline (wOf is L2-hot)
//  - gather loads = SGPR base + 32-bit voffset (+imm for chunk B)
//  - __launch_bounds__(256, 8) forces 64-VGPR allocation -> 8 waves/SIMD
// grid: 2304 blocks with XCD swizzle.
// -------------------------------------------------------------------------
__global__ __launch_bounds__(256, 8) void k_fused(
    const ushort* __restrict__ xtb, const ushort* __restrict__ wOf,
    const float* __restrict__ b_off, const ushort* __restrict__ wBf,
    const float* __restrict__ b_conv, ushort* __restrict__ yt) {
  __shared__ ushort sA[4][2][64][8];                // [wave][ks][lane][j] = 8 KB
  __shared__ __align__(16) float offBuf[4][16][20]; // [wave][pl][oc(18,pad20)] = 5 KB

  const int bid = blockIdx.x;
  const int xcd = bid & 7;
  const int s0 = bid >> 3; // 0..287
  const int b = xcd >> 1;
  const int half = xcd & 1;
  const int th = half * 12 + s0 / 24; // 0..23
  const int tw = s0 % 24;             // 0..23
  const int h0 = th * 8, w0 = tw * 8;

  const int tid = threadIdx.x;
  const int wave = tid >> 6, lane = tid & 63;
  const int col = lane & 15, quad = lane >> 4;
  const int p = tid >> 2, qtr = tid & 3;
  const int pl = p & 15; // wave-local pixel
  const int prow = p >> 3, pcol = p & 7;
  const int h = h0 + prow, w = w0 + pcol;
  const int ks_w = qtr >> 1;    // LDS ks plane for gather writes
  const int q2 = (qtr & 1) * 2; // first quad row

  // ===================== Phase 1: offset conv (per wave) =====================
  {
    float4v oacc[2];
#pragma unroll
    for (int nt = 0; nt < 2; ++nt) oacc[nt] = (float4v){0.f, 0.f, 0.f, 0.f};

    short8 oafr[2][2]; // [pb][ks] — A fragments double-buffered; weights inline

    auto oload = [&](int kk, int pb) {
      const int ky = kk / 3, kx = kk % 3;
      const int hh = h0 + 2 * wave + (col >> 3) + ky - 1;
      const int ww = w0 + (col & 7) + kx - 1;
      const bool ok = ((unsigned)hh < (unsigned)H) && ((unsigned)ww < (unsigned)W);
      const int hhc = min(max(hh, 0), H - 1);
      const int wwc = min(max(ww, 0), W - 1);
      const ushort* pa = xtb + (((size_t)b * H + hhc) * W + wwc) * C + quad * 8;
#pragma unroll
      for (int ks = 0; ks < 2; ++ks) {
        short8 v = (short8)0;
        if (ok) v = *(const short8*)(pa + ks * 32);
        oafr[pb][ks] = v;
      }
    };

    oload(0, 0);
#pragma unroll
    for (int kk = 0; kk < 9; ++kk) {
      const int pb = kk & 1;
      if (kk < 8) oload(kk + 1, pb ^ 1);
#pragma unroll
      for (int ks = 0; ks < 2; ++ks)
#pragma unroll
        for (int nt = 0; nt < 2; ++nt) {
          const short8 bw =
              *(const short8*)&wOf[((((size_t)kk * 2 + ks) * 2 + nt) * 64 + lane) * 8];
          oacc[nt] = __builtin_amdgcn_mfma_f32_16x16x32_bf16(oafr[pb][ks], bw, oacc[nt], 0, 0, 0);
        }
    }

    // distribute offsets: D[m=quad*4+r][n=nt*16+col] -> offBuf[wave][m][oc]
#pragma unroll
    for (int nt = 0; nt < 2; ++nt) {
      const int oc = nt * 16 + col;
      if (oc < OOFF) {
        const float bias = b_off[oc];
#pragma unroll
        for (int r = 0; r < 4; ++r)
          offBuf[wave][quad * 4 + r][oc] = oacc[nt][r] + bias;
      }
    }
  } // intra-wave LDS exchange: no barrier needed (same-wave ds ordering)

  // ===================== Phase 2: deformable conv =====================
  // Wave-uniform base pointer (SGPR pair); per-lane 32-bit byte offsets.
  const ushort* xbase = xtb + (size_t)b * H * W * C;
  const uint qoff = (uint)qtr * 32u; // channel sub-block of this gather thread

  uint offs[2][4]; // [slot][corner] byte offsets (chunk A; chunk B = +16)
  float4 awv[2];   // [slot] bilinear corner weights (validity-masked)
  uint4 gA[4], gB[4]; // single-buffered chunk gather regs (16 VGPR each)

  auto calc = [&](int kk, int s) {
    const float2 ov = *(const float2*)&offBuf[wave][pl][2 * kk];
    const float dy = ov.x, dx = ov.y;
    const int ky = kk / 3, kx = kk % 3;
    const float pyf = dy + (float)(ky + h - 1);
    const float pxf = dx + (float)(kx + w - 1);
    const float fy0 = floorf(pyf), fx0 = floorf(pxf);
    const float wy = pyf - fy0, wx = pxf - fx0;
    const int iy0 = (int)fy0, ix0 = (int)fx0;
    const int iy1 = iy0 + 1, ix1 = ix0 + 1;
    const bool vy0 = (unsigned)iy0 < (unsigned)H;
    const bool vy1 = (unsigned)iy1 < (unsigned)H;
    const bool vx0 = (unsigned)ix0 < (unsigned)W;
    const bool vx1 = (unsigned)ix1 < (unsigned)W;
    awv[s].x = (vy0 && vx0) ? (1.f - wy) * (1.f - wx) : 0.f;
    awv[s].y = (vy0 && vx1) ? (1.f - wy) * wx : 0.f;
    awv[s].z = (vy1 && vx0) ? wy * (1.f - wx) : 0.f;
    awv[s].w = (vy1 && vx1) ? wy * wx : 0.f;
    const int cy0 = min(max(iy0, 0), H - 1), cy1 = min(max(iy1, 0), H - 1);
    const int cx0 = min(max(ix0, 0), W - 1), cx1 = min(max(ix1, 0), W - 1);
    offs[s][0] = (uint)((cy0 * W + cx0) * (C * 2)) + qoff;
    offs[s][1] = (uint)((cy0 * W + cx1) * (C * 2)) + qoff;
    offs[s][2] = (uint)((cy1 * W + cx0) * (C * 2)) + qoff;
    offs[s][3] = (uint)((cy1 * W + cx1) * (C * 2)) + qoff;
  };

  auto loadA = [&](int s) {
#pragma unroll
    for (int c = 0; c < 4; ++c)
      gA[c] = *(const uint4*)((const char*)xbase + offs[s][c]);
  };
  auto loadB = [&](int s) {
#pragma unroll
    for (int c = 0; c < 4; ++c)
      gB[c] = *(const uint4*)((const char*)xbase + offs[s][c] + 16u);
  };
  auto blend = [&](const uint4* g, int s, uint* pk) {
    const f32x2 a00 = {awv[s].x, awv[s].x};
    const f32x2 a01 = {awv[s].y, awv[s].y};
    const f32x2 a10 = {awv[s].z, awv[s].z};
    const f32x2 a11 = {awv[s].w, awv[s].w};
#pragma unroll
    for (int i = 0; i < 4; ++i) {
      f32x2 sv = upk(g[0][i]) * a00 + upk(g[1][i]) * a01 + upk(g[2][i]) * a10 + upk(g[3][i]) * a11;
      pk[i] = pk2bf(sv.x, sv.y);
    }
  };

  float4v acc[4];
#pragma unroll
  for (int nt = 0; nt < 4; ++nt) acc[nt] = (float4v){0.f, 0.f, 0.f, 0.f};

  calc(0, 0);
  loadA(0); // chunk A of kk=0 in flight
#pragma unroll
  for (int kk = 0; kk < 9; ++kk) {
    const int s = kk & 1, ns = s ^ 1;
    loadB(s);                    // chunk B of this kk in flight
    if (kk < 8) calc(kk + 1, ns); // VALU offset math overlaps loads

    uint pkA[4];
    blend(gA, s, pkA); // waits chunk A (issued one kk ago)
    *(uint4*)&sA[wave][ks_w][pl | (q2 << 4)][0] = *(const uint4*)pkA;
    if (kk < 8) loadA(ns); // prefetch next kk's chunk A (covers blendB+MFMA)

    uint pkB[4];
    blend(gB, s, pkB);
    *(uint4*)&sA[wave][ks_w][pl | ((q2 + 1) << 4)][0] = *(const uint4*)pkB;

    // intra-wave exchange: writes above, reads below, same wave => ordered.
#pragma unroll
    for (int ks = 0; ks < 2; ++ks) {
      const short8 a = *(const short8*)&sA[wave][ks][lane][0];
#pragma unroll
      for (int nt = 0; nt < 4; ++nt) {
        const short8 bb = *(const short8*)&wBf[((((size_t)kk * 2 + ks) * 4 + nt) * 64 + lane) * 8];
        acc[nt] = __builtin_amdgcn_mfma_f32_16x16x32_bf16(a, bb, acc[nt], 0, 0, 0);
      }
    }
  }

  // epilogue: yt[b][h][w][c] bf16, oc = nt + 4*(lane&15) (permuted)
  float bias[4];
#pragma unroll
  for (int nt = 0; nt < 4; ++nt) bias[nt] = b_conv[4 * col + nt];
#pragma unroll
  for (int r = 0; r < 4; ++r) {
    const int pp = wave * 16 + quad * 4 + r; // pixel index in 8x8 tile
    const int hrow = h0 + (pp >> 3), wcol = w0 + (pp & 7);
    uint2 u;
    u.x = pk2bf(acc[0][r] + bias[0], acc[1][r] + bias[1]);
    u.y = pk2bf(acc[2][r] + bias[2], acc[3][r] + bias[3]);
    *(uint2*)&yt[((size_t)(b * H + hrow) * W + wcol) * C + 4 * col] = u;
  }
}

// -------------------------------------------------------------------------
// Kernel 4: main 3x3 conv via bf16 MFMA, LDS-free, 1-stage pipelined frags.
// Wave = 2 rows x 64 oc; block = 8 rows; grid (12, 24, 4) = 1152 blocks.
// -------------------------------------------------------------------------
__global__ __launch_bounds__(256) void k_conv_main_mfma(
    const ushort* __restrict__ yt, const ushort* __restrict__ wBf,
    const float* __restrict__ b_conv, float* __restrict__ out) {
  const int w0 = blockIdx.x * 16;
  const int b = blockIdx.z;
  const int tid = threadIdx.x;
  const int wave = tid >> 6, lane = tid & 63;
  const int col = lane & 15, quad = lane >> 4;
  const int h0 = blockIdx.y * 8 + wave * 2;

  float4v acc[2][4];
#pragma unroll
  for (int mt = 0; mt < 2; ++mt)
#pragma unroll
    for (int nt = 0; nt < 4; ++nt) acc[mt][nt] = (float4v){0.f, 0.f, 0.f, 0.f};

  short8 bfr[2][2][4]; // [pb][ks][nt]
  short8 afr[2][2][2]; // [pb][mt][ks]

  auto load = [&](int kk, int pb) {
    const int ky = kk / 3, kx = kk % 3;
    const int ww = w0 + col + kx - 1;
    const bool wok = (unsigned)ww < (unsigned)W;
    const int wwc = min(max(ww, 0), W - 1);
#pragma unroll
    for (int ks = 0; ks < 2; ++ks)
#pragma unroll
      for (int nt = 0; nt < 4; ++nt)
        bfr[pb][ks][nt] = *(const short8*)&wBf[((((size_t)kk * 2 + ks) * 4 + nt) * 64 + lane) * 8];
#pragma unroll
    for (int mt = 0; mt < 2; ++mt) {
      const int hh = h0 + mt + ky - 1;
      const bool ok = wok && ((unsigned)hh < (unsigned)H);
      const int hhc = min(max(hh, 0), H - 1);
      const ushort* pa = yt + (((size_t)b * H + hhc) * W + wwc) * C + quad * 8;
#pragma unroll
      for (int ks = 0; ks < 2; ++ks) {
        short8 v = (short8)0;
        if (ok) v = *(const short8*)(pa + ks * 32);
        afr[pb][mt][ks] = v;
      }
    }
  };

  load(0, 0);
#pragma unroll
  for (int kk = 0; kk < 9; ++kk) {
    const int pb = kk & 1;
    if (kk < 8) load(kk + 1, pb ^ 1);
#pragma unroll
    for (int ks = 0; ks < 2; ++ks)
#pragma unroll
      for (int mt = 0; mt < 2; ++mt)
#pragma unroll
        for (int nt = 0; nt < 4; ++nt)
          acc[mt][nt] = __builtin_amdgcn_mfma_f32_16x16x32_bf16(afr[pb][mt][ks], bfr[pb][ks][nt],
                                                                acc[mt][nt], 0, 0, 0);
  }

  float bias[4];
#pragma unroll
  for (int nt = 0; nt < 4; ++nt) bias[nt] = b_conv[4 * col + nt];
#pragma unroll
  for (int mt = 0; mt < 2; ++mt) {
    const int h = h0 + mt;
#pragma unroll
    for (int nt = 0; nt < 4; ++nt) {
      const int oc = 4 * col + nt; // permuted C/D col -> oc
      float4 v;
      v.x = acc[mt][nt][0] + bias[nt];
      v.y = acc[mt][nt][1] + bias[nt];
      v.z = acc[mt][nt][2] + bias[nt];
      v.w = acc[mt][nt][3] + bias[nt];
      *(float4*)&out[(((size_t)b * O + oc) * H + h) * W + w0 + quad * 4] = v;
    }
  }
}

// -------------------------------------------------------------------------
extern "C" void kernel_launch(void* const* d_in, const int* in_sizes, int n_in,
                              void* d_out, int out_size, void* d_ws, size_t ws_size,
                              hipStream_t stream) {
  const float* x = (const float*)d_in[0];
  const float* w_off = (const float*)d_in[1];
  const float* b_off = (const float*)d_in[2];
  const float* w_conv = (const float*)d_in[3];
  const float* b_conv = (const float*)d_in[4];
  float* out = (float*)d_out;

  ushort* xtb = (ushort*)d_ws;              // B*H*W*C bf16
  ushort* yt = xtb + (size_t)B * H * W * C; // B*H*W*C bf16
  ushort* wBf = yt + (size_t)B * H * W * C; // 36864 bf16
  ushort* wOf = wBf + 36864;                // 18432 bf16

  const dim3 blk(256);
  k_pre<<<dim3(9432), blk, 0, stream>>>(x, xtb, w_conv, wBf, w_off, wOf);
  k_fused<<<dim3(2304), blk, 0, stream>>>(xtb, wOf, b_off, wBf, b_conv, yt);
  k_conv_main_mfma<<<dim3(W / 16, H / 8, B), blk, 0, stream>>>(yt, wBf, b_conv, out);
}

// Round 2
// 199.259 us; speedup vs baseline: 1.4699x; 1.4699x over previous
//
#include <hip/hip_runtime.h>

// Problem constants (fixed by setup_inputs)
constexpr int B = 4;
constexpr int C = 64;    // input channels
constexpr int O = 64;    // output channels (main conv)
constexpr int OOFF = 18; // offset channels = 2*3*3
constexpr int H = 192;
constexpr int W = 192;

typedef __attribute__((ext_vector_type(8))) short short8;   // 8 bf16 = 4 VGPR
typedef __attribute__((ext_vector_type(4))) float float4v;  // MFMA acc
typedef __attribute__((ext_vector_type(2))) float f32x2;    // v_pk_fma_f32 pair
typedef __attribute__((ext_vector_type(2))) uint u32x2;
typedef __attribute__((ext_vector_type(2))) __bf16 bf16x2;

__device__ inline ushort f2bf(float f) { // RNE via HW __bf16 convert
  return __builtin_bit_cast(ushort, (__bf16)f);
}
__device__ inline uint pk2bf(float lo, float hi) { // pack 2 bf16 (RNE)
  bf16x2 v;
  v.x = (__bf16)lo;
  v.y = (__bf16)hi;
  return __builtin_bit_cast(uint, v);
}
__device__ inline f32x2 upk(uint u) { // unpack 2 bf16 -> 2 f32
  u32x2 t;
  t.x = u << 16;
  t.y = u & 0xffff0000u;
  return __builtin_bit_cast(f32x2, t);
}

// -------------------------------------------------------------------------
// Kernel PRE (fused): blocks [0,9216): transpose x fp32 NCHW -> xtb bf16
// channels-last. [9216,9360): w_conv -> wBf (PERMUTED n-map oc = nt+4*col).
// [9360,9432): w_off -> wOf (plain n-map, N padded 18->32).
// -------------------------------------------------------------------------
__global__ __launch_bounds__(256) void k_pre(const float* __restrict__ x,
                                             ushort* __restrict__ xtb,
                                             const float* __restrict__ w_conv,
                                             ushort* __restrict__ wBf,
                                             const float* __restrict__ w_off,
                                             ushort* __restrict__ wOf) {
  __shared__ float tile[64][17];
  const int bid = blockIdx.x;
  const int tid = threadIdx.x;
  if (bid < 9216) { // transpose
    const int w0 = (bid % 12) * 16;
    const int h = (bid / 12) % 192;
    const int b = bid / 2304;
    const int wl = tid & 15;
    const int c0 = tid >> 4;
#pragma unroll
    for (int r = 0; r < 4; ++r) {
      const int c = c0 + r * 16;
      tile[c][wl] = x[(((size_t)b * C + c) * H + h) * W + w0 + wl];
    }
    __syncthreads();
    const int c = tid & 63;
    const int qq = tid >> 6;
#pragma unroll
    for (int r = 0; r < 4; ++r) {
      const int wq = qq + r * 4;
      xtb[(((size_t)b * H + h) * W + w0 + wq) * C + c] = f2bf(tile[c][wq]);
    }
  } else if (bid < 9360) { // wBf: 36864 entries
    const int i = (bid - 9216) * 256 + tid;
    const int j = i & 7;
    const int lane = (i >> 3) & 63;
    const int nt = (i >> 9) & 3;
    const int kstep = (i >> 11) & 1;
    const int kk = i >> 12;
    const int n = nt + 4 * (lane & 15); // permuted
    const int c = kstep * 32 + ((lane >> 4) & 3) * 8 + j;
    wBf[i] = f2bf(w_conv[((size_t)n * C + c) * 9 + kk]);
  } else { // wOf: 18432 entries
    const int i = (bid - 9360) * 256 + tid;
    const int j = i & 7;
    const int lane = (i >> 3) & 63;
    const int nt = (i >> 9) & 1;
    const int ks = (i >> 10) & 1;
    const int kk = i >> 11;
    const int n = nt * 16 + (lane & 15);
    const int c = ks * 32 + ((lane >> 4) & 3) * 8 + j;
    wOf[i] = (n < OOFF) ? f2bf(w_off[((size_t)n * C + c) * 9 + kk]) : (ushort)0;
  }
}

// -------------------------------------------------------------------------
// Kernel FUSED: offset-conv + deformable conv, BARRIER-FREE.
// 8x8 px tile, 256 threads = 4 waves. All LDS exchange is intra-wave
// (gather thread (p,qtr) and MFMA lane for pixel p&15 share a wave), so no
// __syncthreads anywhere — waves run fully decoupled pipelines.
// Register-dieted gather pipeline (chunked: 2x16 regs in flight, inline
// phase-1 weights, SGPR-base + 32-bit voffset gathers) so the compiler can
// keep the one-kk-ahead prefetch REAL instead of de-pipelining (round-0
// G[2][8]=64 regs could not be live within a 68-reg allocation).
// NO min-waves forcing: round-1's __launch_bounds__(256,8) caused ~450 MB
// of scratch spill traffic per dispatch (FETCH 10->180MB, WRITE 18->271MB)
// and doubled duration. Let the allocator pick; hope for <=64 VGPR.
// grid: 2304 blocks with XCD swizzle.
// -------------------------------------------------------------------------
__global__ __launch_bounds__(256) void k_fused(
    const ushort* __restrict__ xtb, const ushort* __restrict__ wOf,
    const float* __restrict__ b_off, const ushort* __restrict__ wBf,
    const float* __restrict__ b_conv, ushort* __restrict__ yt) {
  __shared__ ushort sA[4][2][64][8];                // [wave][ks][lane][j] = 8 KB
  __shared__ __align__(16) float offBuf[4][16][20]; // [wave][pl][oc(18,pad20)] = 5 KB

  const int bid = blockIdx.x;
  const int xcd = bid & 7;
  const int s0 = bid >> 3; // 0..287
  const int b = xcd >> 1;
  const int half = xcd & 1;
  const int th = half * 12 + s0 / 24; // 0..23
  const int tw = s0 % 24;             // 0..23
  const int h0 = th * 8, w0 = tw * 8;

  const int tid = threadIdx.x;
  const int wave = tid >> 6, lane = tid & 63;
  const int col = lane & 15, quad = lane >> 4;
  const int p = tid >> 2, qtr = tid & 3;
  const int pl = p & 15; // wave-local pixel
  const int prow = p >> 3, pcol = p & 7;
  const int h = h0 + prow, w = w0 + pcol;
  const int ks_w = qtr >> 1;    // LDS ks plane for gather writes
  const int q2 = (qtr & 1) * 2; // first quad row

  // ===================== Phase 1: offset conv (per wave) =====================
  {
    float4v oacc[2];
#pragma unroll
    for (int nt = 0; nt < 2; ++nt) oacc[nt] = (float4v){0.f, 0.f, 0.f, 0.f};

    short8 oafr[2][2]; // [pb][ks] — A fragments double-buffered; weights inline

    auto oload = [&](int kk, int pb) {
      const int ky = kk / 3, kx = kk % 3;
      const int hh = h0 + 2 * wave + (col >> 3) + ky - 1;
      const int ww = w0 + (col & 7) + kx - 1;
      const bool ok = ((unsigned)hh < (unsigned)H) && ((unsigned)ww < (unsigned)W);
      const int hhc = min(max(hh, 0), H - 1);
      const int wwc = min(max(ww, 0), W - 1);
      const ushort* pa = xtb + (((size_t)b * H + hhc) * W + wwc) * C + quad * 8;
#pragma unroll
      for (int ks = 0; ks < 2; ++ks) {
        short8 v = (short8)0;
        if (ok) v = *(const short8*)(pa + ks * 32);
        oafr[pb][ks] = v;
      }
    };

    oload(0, 0);
#pragma unroll
    for (int kk = 0; kk < 9; ++kk) {
      const int pb = kk & 1;
      if (kk < 8) oload(kk + 1, pb ^ 1);
#pragma unroll
      for (int ks = 0; ks < 2; ++ks)
#pragma unroll
        for (int nt = 0; nt < 2; ++nt) {
          const short8 bw =
              *(const short8*)&wOf[((((size_t)kk * 2 + ks) * 2 + nt) * 64 + lane) * 8];
          oacc[nt] = __builtin_amdgcn_mfma_f32_16x16x32_bf16(oafr[pb][ks], bw, oacc[nt], 0, 0, 0);
        }
    }

    // distribute offsets: D[m=quad*4+r][n=nt*16+col] -> offBuf[wave][m][oc]
#pragma unroll
    for (int nt = 0; nt < 2; ++nt) {
      const int oc = nt * 16 + col;
      if (oc < OOFF) {
        const float bias = b_off[oc];
#pragma unroll
        for (int r = 0; r < 4; ++r)
          offBuf[wave][quad * 4 + r][oc] = oacc[nt][r] + bias;
      }
    }
  } // intra-wave LDS exchange: no barrier needed (same-wave ds ordering)

  // ===================== Phase 2: deformable conv =====================
  // Wave-uniform base pointer (SGPR pair); per-lane 32-bit byte offsets.
  const ushort* xbase = xtb + (size_t)b * H * W * C;
  const uint qoff = (uint)qtr * 32u; // channel sub-block of this gather thread

  uint offs[2][4];    // [slot][corner] byte offsets (chunk A; chunk B = +16)
  float4 awv[2];      // [slot] bilinear corner weights (validity-masked)
  uint4 gA[4], gB[4]; // single-buffered chunk gather regs (16 VGPR each)

  auto calc = [&](int kk, int s) {
    const float2 ov = *(const float2*)&offBuf[wave][pl][2 * kk];
    const float dy = ov.x, dx = ov.y;
    const int ky = kk / 3, kx = kk % 3;
    const float pyf = dy + (float)(ky + h - 1);
    const float pxf = dx + (float)(kx + w - 1);
    const float fy0 = floorf(pyf), fx0 = floorf(pxf);
    const float wy = pyf - fy0, wx = pxf - fx0;
    const int iy0 = (int)fy0, ix0 = (int)fx0;
    const int iy1 = iy0 + 1, ix1 = ix0 + 1;
    const bool vy0 = (unsigned)iy0 < (unsigned)H;
    const bool vy1 = (unsigned)iy1 < (unsigned)H;
    const bool vx0 = (unsigned)ix0 < (unsigned)W;
    const bool vx1 = (unsigned)ix1 < (unsigned)W;
    awv[s].x = (vy0 && vx0) ? (1.f - wy) * (1.f - wx) : 0.f;
    awv[s].y = (vy0 && vx1) ? (1.f - wy) * wx : 0.f;
    awv[s].z = (vy1 && vx0) ? wy * (1.f - wx) : 0.f;
    awv[s].w = (vy1 && vx1) ? wy * wx : 0.f;
    const int cy0 = min(max(iy0, 0), H - 1), cy1 = min(max(iy1, 0), H - 1);
    const int cx0 = min(max(ix0, 0), W - 1), cx1 = min(max(ix1, 0), W - 1);
    offs[s][0] = (uint)((cy0 * W + cx0) * (C * 2)) + qoff;
    offs[s][1] = (uint)((cy0 * W + cx1) * (C * 2)) + qoff;
    offs[s][2] = (uint)((cy1 * W + cx0) * (C * 2)) + qoff;
    offs[s][3] = (uint)((cy1 * W + cx1) * (C * 2)) + qoff;
  };

  auto loadA = [&](int s) {
#pragma unroll
    for (int c = 0; c < 4; ++c)
      gA[c] = *(const uint4*)((const char*)xbase + offs[s][c]);
  };
  auto loadB = [&](int s) {
#pragma unroll
    for (int c = 0; c < 4; ++c)
      gB[c] = *(const uint4*)((const char*)xbase + offs[s][c] + 16u);
  };
  auto blend = [&](const uint4* g, int s, uint* pk) {
    const f32x2 a00 = {awv[s].x, awv[s].x};
    const f32x2 a01 = {awv[s].y, awv[s].y};
    const f32x2 a10 = {awv[s].z, awv[s].z};
    const f32x2 a11 = {awv[s].w, awv[s].w};
#pragma unroll
    for (int i = 0; i < 4; ++i) {
      f32x2 sv = upk(g[0][i]) * a00 + upk(g[1][i]) * a01 + upk(g[2][i]) * a10 + upk(g[3][i]) * a11;
      pk[i] = pk2bf(sv.x, sv.y);
    }
  };

  float4v acc[4];
#pragma unroll
  for (int nt = 0; nt < 4; ++nt) acc[nt] = (float4v){0.f, 0.f, 0.f, 0.f};

  calc(0, 0);
  loadA(0); // chunk A of kk=0 in flight
#pragma unroll
  for (int kk = 0; kk < 9; ++kk) {
    const int s = kk & 1, ns = s ^ 1;
    loadB(s);                     // chunk B of this kk in flight
    if (kk < 8) calc(kk + 1, ns); // VALU offset math overlaps loads

    uint pkA[4];
    blend(gA, s, pkA); // waits chunk A (issued one kk ago)
    *(uint4*)&sA[wave][ks_w][pl | (q2 << 4)][0] = *(const uint4*)pkA;
    if (kk < 8) loadA(ns); // prefetch next kk's chunk A (covers blendB+MFMA)

    uint pkB[4];
    blend(gB, s, pkB);
    *(uint4*)&sA[wave][ks_w][pl | ((q2 + 1) << 4)][0] = *(const uint4*)pkB;

    // intra-wave exchange: writes above, reads below, same wave => ordered.
#pragma unroll
    for (int ks = 0; ks < 2; ++ks) {
      const short8 a = *(const short8*)&sA[wave][ks][lane][0];
#pragma unroll
      for (int nt = 0; nt < 4; ++nt) {
        const short8 bb = *(const short8*)&wBf[((((size_t)kk * 2 + ks) * 4 + nt) * 64 + lane) * 8];
        acc[nt] = __builtin_amdgcn_mfma_f32_16x16x32_bf16(a, bb, acc[nt], 0, 0, 0);
      }
    }
  }

  // epilogue: yt[b][h][w][c] bf16, oc = nt + 4*(lane&15) (permuted)
  float bias[4];
#pragma unroll
  for (int nt = 0; nt < 4; ++nt) bias[nt] = b_conv[4 * col + nt];
#pragma unroll
  for (int r = 0; r < 4; ++r) {
    const int pp = wave * 16 + quad * 4 + r; // pixel index in 8x8 tile
    const int hrow = h0 + (pp >> 3), wcol = w0 + (pp & 7);
    uint2 u;
    u.x = pk2bf(acc[0][r] + bias[0], acc[1][r] + bias[1]);
    u.y = pk2bf(acc[2][r] + bias[2], acc[3][r] + bias[3]);
    *(uint2*)&yt[((size_t)(b * H + hrow) * W + wcol) * C + 4 * col] = u;
  }
}

// -------------------------------------------------------------------------
// Kernel 4: main 3x3 conv via bf16 MFMA, LDS-free, 1-stage pipelined frags.
// Wave = 2 rows x 64 oc; block = 8 rows; grid (12, 24, 4) = 1152 blocks.
// -------------------------------------------------------------------------
__global__ __launch_bounds__(256) void k_conv_main_mfma(
    const ushort* __restrict__ yt, const ushort* __restrict__ wBf,
    const float* __restrict__ b_conv, float* __restrict__ out) {
  const int w0 = blockIdx.x * 16;
  const int b = blockIdx.z;
  const int tid = threadIdx.x;
  const int wave = tid >> 6, lane = tid & 63;
  const int col = lane & 15, quad = lane >> 4;
  const int h0 = blockIdx.y * 8 + wave * 2;

  float4v acc[2][4];
#pragma unroll
  for (int mt = 0; mt < 2; ++mt)
#pragma unroll
    for (int nt = 0; nt < 4; ++nt) acc[mt][nt] = (float4v){0.f, 0.f, 0.f, 0.f};

  short8 bfr[2][2][4]; // [pb][ks][nt]
  short8 afr[2][2][2]; // [pb][mt][ks]

  auto load = [&](int kk, int pb) {
    const int ky = kk / 3, kx = kk % 3;
    const int ww = w0 + col + kx - 1;
    const bool wok = (unsigned)ww < (unsigned)W;
    const int wwc = min(max(ww, 0), W - 1);
#pragma unroll
    for (int ks = 0; ks < 2; ++ks)
#pragma unroll
      for (int nt = 0; nt < 4; ++nt)
        bfr[pb][ks][nt] = *(const short8*)&wBf[((((size_t)kk * 2 + ks) * 4 + nt) * 64 + lane) * 8];
#pragma unroll
    for (int mt = 0; mt < 2; ++mt) {
      const int hh = h0 + mt + ky - 1;
      const bool ok = wok && ((unsigned)hh < (unsigned)H);
      const int hhc = min(max(hh, 0), H - 1);
      const ushort* pa = yt + (((size_t)b * H + hhc) * W + wwc) * C + quad * 8;
#pragma unroll
      for (int ks = 0; ks < 2; ++ks) {
        short8 v = (short8)0;
        if (ok) v = *(const short8*)(pa + ks * 32);
        afr[pb][mt][ks] = v;
      }
    }
  };

  load(0, 0);
#pragma unroll
  for (int kk = 0; kk < 9; ++kk) {
    const int pb = kk & 1;
    if (kk < 8) load(kk + 1, pb ^ 1);
#pragma unroll
    for (int ks = 0; ks < 2; ++ks)
#pragma unroll
      for (int mt = 0; mt < 2; ++mt)
#pragma unroll
        for (int nt = 0; nt < 4; ++nt)
          acc[mt][nt] = __builtin_amdgcn_mfma_f32_16x16x32_bf16(afr[pb][mt][ks], bfr[pb][ks][nt],
                                                                acc[mt][nt], 0, 0, 0);
  }

  float bias[4];
#pragma unroll
  for (int nt = 0; nt < 4; ++nt) bias[nt] = b_conv[4 * col + nt];
#pragma unroll
  for (int mt = 0; mt < 2; ++mt) {
    const int h = h0 + mt;
#pragma unroll
    for (int nt = 0; nt < 4; ++nt) {
      const int oc = 4 * col + nt; // permuted C/D col -> oc
      float4 v;
      v.x = acc[mt][nt][0] + bias[nt];
      v.y = acc[mt][nt][1] + bias[nt];
      v.z = acc[mt][nt][2] + bias[nt];
      v.w = acc[mt][nt][3] + bias[nt];
      *(float4*)&out[(((size_t)b * O + oc) * H + h) * W + w0 + quad * 4] = v;
    }
  }
}

// -------------------------------------------------------------------------
extern "C" void kernel_launch(void* const* d_in, const int* in_sizes, int n_in,
                              void* d_out, int out_size, void* d_ws, size_t ws_size,
                              hipStream_t stream) {
  const float* x = (const float*)d_in[0];
  const float* w_off = (const float*)d_in[1];
  const float* b_off = (const float*)d_in[2];
  const float* w_conv = (const float*)d_in[3];
  const float* b_conv = (const float*)d_in[4];
  float* out = (float*)d_out;

  ushort* xtb = (ushort*)d_ws;              // B*H*W*C bf16
  ushort* yt = xtb + (size_t)B * H * W * C; // B*H*W*C bf16
  ushort* wBf = yt + (size_t)B * H * W * C; // 36864 bf16
  ushort* wOf = wBf + 36864;                // 18432 bf16

  const dim3 blk(256);
  k_pre<<<dim3(9432), blk, 0, stream>>>(x, xtb, w_conv, wBf, w_off, wOf);
  k_fused<<<dim3(2304), blk, 0, stream>>>(xtb, wOf, b_off, wBf, b_conv, yt);
  k_conv_main_mfma<<<dim3(W / 16, H / 8, B), blk, 0, stream>>>(yt, wBf, b_conv, out);
}